// Round 5
// baseline (317.547 us; speedup 1.0000x reference)
//
#include <hip/hip_runtime.h>

#define WIN      2048
#define HOP      512
#define NFRAMES  16384
#define NBINS    1025      // WIN/2 + 1
#define FPB      8         // frames per block
#define WAVES    4         // one wave per in-flight frame
#define ACCN     (FPB * HOP + (WIN - HOP))   // 5632 floats

// ---------------------------------------------------------------------------
// init: synthesis window rs[j] = (hamming/sqrt(4094)) / env, folded with the
// 1/1024 normalization of the half-size complex IFFT.
// ---------------------------------------------------------------------------
__global__ void init_rs_kernel(float* __restrict__ rs) {
    int i = blockIdx.x * blockDim.x + threadIdx.x;
    if (i >= WIN) return;
    const float inv2047 = 1.0f / 2047.0f;
    const float scale   = rsqrtf(4094.0f);
    float sw = (0.54f - 0.46f * cospif(2.0f * (float)i * inv2047)) * scale;
    int   m0 = i & 511;
    float env = 0.0f;
    #pragma unroll
    for (int r = 0; r < 4; ++r) {
        int   m = m0 + 512 * r;
        float h = (0.54f - 0.46f * cospif(2.0f * (float)m * inv2047)) * scale;
        env += h * h;
    }
    rs[i] = sw / env * (1.0f / 1024.0f);
}

__device__ __forceinline__ float2 cmul(float2 a, float2 b) {
    return make_float2(a.x * b.x - a.y * b.y, a.x * b.y + a.y * b.x);
}

// inverse radix-4 butterfly: F[m] = sum_j z[j] * i^(j*m), results in place
__device__ __forceinline__ void ifft4(float2& a, float2& b, float2& c, float2& d) {
    float2 t0 = make_float2(a.x + c.x, a.y + c.y);
    float2 t1 = make_float2(a.x - c.x, a.y - c.y);
    float2 t2 = make_float2(b.x + d.x, b.y + d.y);
    float2 t3 = make_float2(b.x - d.x, b.y - d.y);
    float2 i3 = make_float2(-t3.y, t3.x);           // i*(b-d)
    a = make_float2(t0.x + t2.x, t0.y + t2.y);
    b = make_float2(t1.x + i3.x, t1.y + i3.y);
    c = make_float2(t0.x - t2.x, t0.y - t2.y);
    d = make_float2(t1.x - i3.x, t1.y - i3.y);
}

// inverse 16-pt FFT: A[m] = sum_p z[p] e^{2pi i pm/16}.
// p = p0+4p1, m = m0+4m1. After: A[m0+4m1] sits at z[4*m0 + m1],
// i.e. A[m] at z[4*(m&3) + (m>>2)].
__device__ __forceinline__ void ifft16(float2* z) {
    ifft4(z[0], z[4], z[8],  z[12]);
    ifft4(z[1], z[5], z[9],  z[13]);
    ifft4(z[2], z[6], z[10], z[14]);
    ifft4(z[3], z[7], z[11], z[15]);
    const float C8  = 0.70710678118654752f;
    const float C16 = 0.92387953251128676f, S16 = 0.38268343236508977f;
    // slot p0+4*m0 *= w16^(p0*m0), w16 = e^{2pi i/16}
    z[5]  = cmul(z[5],  make_float2( C16,  S16));   // e=1
    z[9]  = cmul(z[9],  make_float2( C8,   C8 ));   // e=2
    z[13] = cmul(z[13], make_float2( S16,  C16));   // e=3
    z[6]  = cmul(z[6],  make_float2( C8,   C8 ));   // e=2
    z[10] = make_float2(-z[10].y, z[10].x);         // e=4 (mul by i)
    z[14] = cmul(z[14], make_float2(-C8,   C8 ));   // e=6
    z[7]  = cmul(z[7],  make_float2( S16,  C16));   // e=3
    z[11] = cmul(z[11], make_float2(-C8,   C8 ));   // e=6
    z[15] = cmul(z[15], make_float2(-C16, -S16));   // e=9
    ifft4(z[0],  z[1],  z[2],  z[3]);
    ifft4(z[4],  z[5],  z[6],  z[7]);
    ifft4(z[8],  z[9],  z[10], z[11]);
    ifft4(z[12], z[13], z[14], z[15]);
}

#define LDS_FENCE() do { \
    asm volatile("s_waitcnt lgkmcnt(0)" ::: "memory"); \
    __builtin_amdgcn_sched_barrier(0); \
} while (0)

// cos/sin(pi*p/16), p=0..15 (pack rotation constants)
__device__ __constant__ float ROTC[16] = {
    1.0f, 0.98078528f, 0.92387953f, 0.83146961f, 0.70710678f, 0.55557023f,
    0.38268343f, 0.19509032f, 0.0f, -0.19509032f, -0.38268343f, -0.55557023f,
    -0.70710678f, -0.83146961f, -0.92387953f, -0.98078528f };
__device__ __constant__ float ROTS[16] = {
    0.0f, 0.19509032f, 0.38268343f, 0.55557023f, 0.70710678f, 0.83146961f,
    0.92387953f, 0.98078528f, 1.0f, 0.98078528f, 0.92387953f, 0.83146961f,
    0.70710678f, 0.55557023f, 0.38268343f, 0.19509032f };

// ---------------------------------------------------------------------------
// 256 threads = 4 waves; wave w handles frames (blk*8 + w) and (blk*8 + w+4).
// Per frame (all wave-private, no __syncthreads in the loop):
//  P1: pack Zf from global (Hermitian half-spectrum trick) for f = q+64p,
//      in-register iFFT16 over p, twiddle by wq^m, store B[q,m] to LDS.
//  P2a: read b[r+16s,m] (r=4g..4g+3), iFFT4 over s, twiddle w64^{ru}, store D.
//  P2b: read D[r,g,m] r=0..15, iFFT16 over r -> y[m+16g+64v].
//  OLA: fftshift+window -> ds_add_f32 into shared acc (frames overlap).
// Layout rotation: addr(row m, col q) = 64m + ((q+m)&63)  [write-side clean].
// ---------------------------------------------------------------------------
__global__ __launch_bounds__(256, 2) void istft_kernel(
        const float* __restrict__ mag, const float* __restrict__ ph,
        const float* __restrict__ rs, float* __restrict__ out, int out_size) {
    __shared__ float2 fbuf[WAVES * 1024];    // 32 KB: 8 KB per wave
    __shared__ float  acc[ACCN];             // 22.5 KB shared OLA buffer

    const int tid  = threadIdx.x;
    const int wave = tid >> 6;
    const int lane = tid & 63;
    const int m_   = lane & 15;
    const int g_   = lane >> 4;
    float2* buf = fbuf + wave * 1024;
    const int frame0 = blockIdx.x * FPB;

    for (int i = tid; i < ACCN; i += 256) acc[i] = 0.0f;

    // ---- frame-invariant per-lane constants ----
    float2 wpq;                                   // e^{i pi q/1024}
    sincospif((float)lane * (1.0f / 1024.0f), &wpq.y, &wpq.x);
    float2 wq = cmul(wpq, wpq);                   // e^{2pi i q/1024}
    float2 wqp[16];
    wqp[0] = make_float2(1.0f, 0.0f);
    #pragma unroll
    for (int m = 1; m < 16; ++m) wqp[m] = cmul(wqp[m - 1], wq);
    float2 tw64[4][3];                            // e^{2pi i (4g+i)u/64}, u=1..3
    #pragma unroll
    for (int i = 0; i < 4; ++i)
        #pragma unroll
        for (int u = 1; u < 4; ++u)
            sincospif((float)((4 * g_ + i) * u) * (1.0f / 32.0f),
                      &tw64[i][u - 1].y, &tw64[i][u - 1].x);
    const float2* rs2 = (const float2*)rs;
    float2 rsv[16];                               // rs2[lane + 64w]
    #pragma unroll
    for (int w = 0; w < 16; ++w) rsv[w] = rs2[lane + 64 * w];

    __syncthreads();                              // acc zero visible

    for (int j = 0; j < FPB / WAVES; ++j) {
        const int fi    = wave + WAVES * j;
        const size_t fb = (size_t)(frame0 + fi) * NBINS;
        const float* magf = mag + fb;
        const float* phf  = ph  + fb;

        // ---- P1: pack + iFFT16 over p ----
        float2 z[16];
        #pragma unroll
        for (int p = 0; p < 16; ++p) {
            const int k  = lane + 64 * p;
            const int mk = 1024 - k;
            float s, c;
            float mgk = magf[k], phk = phf[k];
            float mgm = magf[mk], phm = phf[mk];
            __sincosf(phk, &s, &c);
            float2 Xk = make_float2(mgk * c, mgk * s);
            __sincosf(phm, &s, &c);
            float2 Xm = make_float2(mgm * c, mgm * s);
            if (k == 0) { Xk.y = 0.0f; Xm.y = 0.0f; }   // DC & Nyquist imag
            // tp = e^{i pi k/1024} = wpq * e^{i pi p/16}
            float2 tp = make_float2(ROTC[p] * wpq.x - ROTS[p] * wpq.y,
                                    ROTC[p] * wpq.y + ROTS[p] * wpq.x);
            float Er = 0.5f * (Xk.x + Xm.x), Ei = 0.5f * (Xk.y - Xm.y);
            float Tr = Xm.x - Xk.x,          Ti = -(Xm.y + Xk.y);
            float Or = 0.5f * (tp.x * Ti + tp.y * Tr);
            float Oi = 0.5f * (tp.y * Ti - tp.x * Tr);
            z[p] = make_float2(Er + Or, Ei + Oi);
        }
        ifft16(z);

        // previous frame's LDS reads are long done (OLA consumed them), but
        // fence before overwriting the buffer to be airtight.
        LDS_FENCE();
        #pragma unroll
        for (int m = 0; m < 16; ++m) {
            float2 B = cmul(z[4 * (m & 3) + (m >> 2)], wqp[m]);
            buf[64 * m + ((lane + m) & 63)] = B;
        }
        LDS_FENCE();

        // ---- P2a: iFFT4 over s + twiddle, in place ----
        float2 br[4][4];
        #pragma unroll
        for (int i = 0; i < 4; ++i)
            #pragma unroll
            for (int s = 0; s < 4; ++s)
                br[i][s] = buf[64 * m_ + ((4 * g_ + i + 16 * s + m_) & 63)];
        // writes depend on all reads via registers -> no fence needed before
        #pragma unroll
        for (int i = 0; i < 4; ++i) {
            ifft4(br[i][0], br[i][1], br[i][2], br[i][3]);
            br[i][1] = cmul(br[i][1], tw64[i][0]);
            br[i][2] = cmul(br[i][2], tw64[i][1]);
            br[i][3] = cmul(br[i][3], tw64[i][2]);
        }
        #pragma unroll
        for (int i = 0; i < 4; ++i)
            #pragma unroll
            for (int u = 0; u < 4; ++u)
                buf[64 * m_ + ((4 * g_ + i + 16 * u + m_) & 63)] = br[i][u];
        LDS_FENCE();

        // ---- P2b: iFFT16 over r ----
        float2 d[16];
        #pragma unroll
        for (int r = 0; r < 16; ++r)
            d[r] = buf[64 * m_ + ((r + 16 * g_ + m_) & 63)];
        ifft16(d);

        // ---- OLA: y[n], n = m_+16g_+64v ; t2 = m_+16g_+64*((v+8)&15) ----
        const int aBase = fi * HOP;
        #pragma unroll
        for (int v = 0; v < 16; ++v) {
            float2 y = d[4 * (v & 3) + (v >> 2)];
            const int w  = (v + 8) & 15;
            const int t2 = m_ + 16 * g_ + 64 * w;
            const float2 r = rsv[w];
            __hip_atomic_fetch_add(&acc[aBase + 2 * t2],     y.x * r.x,
                                   __ATOMIC_RELAXED, __HIP_MEMORY_SCOPE_WORKGROUP);
            __hip_atomic_fetch_add(&acc[aBase + 2 * t2 + 1], y.y * r.y,
                                   __ATOMIC_RELAXED, __HIP_MEMORY_SCOPE_WORKGROUP);
        }
    }
    __syncthreads();

    // writeback: p = frame0*HOP + a - 1536; interior plain, seams atomic
    const int base = frame0 * HOP - 1536;
    for (int a = tid; a < ACCN; a += 256) {
        int p = base + a;
        if (p < 0 || p >= out_size) continue;
        float v = acc[a];
        if (a >= (WIN - HOP) && a < FPB * HOP) out[p] = v;
        else                                   atomicAdd(out + p, v);
    }
}

extern "C" void kernel_launch(void* const* d_in, const int* in_sizes, int n_in,
                              void* d_out, int out_size, void* d_ws, size_t ws_size,
                              hipStream_t stream) {
    const float* mag = (const float*)d_in[0];
    const float* ph  = (const float*)d_in[1];
    float* out = (float*)d_out;
    float* rs  = (float*)d_ws;

    hipMemsetAsync(d_out, 0, (size_t)out_size * sizeof(float), stream);
    init_rs_kernel<<<(WIN + 255) / 256, 256, 0, stream>>>(rs);
    istft_kernel<<<NFRAMES / FPB, 256, 0, stream>>>(mag, ph, rs, out, out_size);
}

// Round 6
// 270.209 us; speedup vs baseline: 1.1752x; 1.1752x over previous
//
#include <hip/hip_runtime.h>

#define WIN      2048
#define HOP      512
#define NFRAMES  16384
#define NBINS    1025      // WIN/2 + 1
#define FPB      8         // frames per block
#define WAVES    4         // one wave per in-flight frame
#define ACCN     (FPB * HOP + (WIN - HOP))   // 5632 floats

// ---------------------------------------------------------------------------
// init: synthesis window rs[j] = (hamming/sqrt(4094)) / env, folded with the
// 1/1024 normalization of the half-size complex IFFT.
// ---------------------------------------------------------------------------
__global__ void init_rs_kernel(float* __restrict__ rs) {
    int i = blockIdx.x * blockDim.x + threadIdx.x;
    if (i >= WIN) return;
    const float inv2047 = 1.0f / 2047.0f;
    const float scale   = rsqrtf(4094.0f);
    float sw = (0.54f - 0.46f * cospif(2.0f * (float)i * inv2047)) * scale;
    int   m0 = i & 511;
    float env = 0.0f;
    #pragma unroll
    for (int r = 0; r < 4; ++r) {
        int   m = m0 + 512 * r;
        float h = (0.54f - 0.46f * cospif(2.0f * (float)m * inv2047)) * scale;
        env += h * h;
    }
    rs[i] = sw / env * (1.0f / 1024.0f);
}

__device__ __forceinline__ float2 cmul(float2 a, float2 b) {
    return make_float2(a.x * b.x - a.y * b.y, a.x * b.y + a.y * b.x);
}

// inverse radix-4 butterfly: F[m] = sum_j z[j] * i^(j*m), in place
__device__ __forceinline__ void ifft4(float2& a, float2& b, float2& c, float2& d) {
    float2 t0 = make_float2(a.x + c.x, a.y + c.y);
    float2 t1 = make_float2(a.x - c.x, a.y - c.y);
    float2 t2 = make_float2(b.x + d.x, b.y + d.y);
    float2 t3 = make_float2(b.x - d.x, b.y - d.y);
    float2 i3 = make_float2(-t3.y, t3.x);           // i*(b-d)
    a = make_float2(t0.x + t2.x, t0.y + t2.y);
    b = make_float2(t1.x + i3.x, t1.y + i3.y);
    c = make_float2(t0.x - t2.x, t0.y - t2.y);
    d = make_float2(t1.x - i3.x, t1.y - i3.y);
}

// inverse 16-pt FFT: A[m] = sum_p z[p] e^{2pi i pm/16}; A[m] ends at
// slot 4*(m&3) + (m>>2).
__device__ __forceinline__ void ifft16(float2* z) {
    ifft4(z[0], z[4], z[8],  z[12]);
    ifft4(z[1], z[5], z[9],  z[13]);
    ifft4(z[2], z[6], z[10], z[14]);
    ifft4(z[3], z[7], z[11], z[15]);
    const float C8  = 0.70710678118654752f;
    const float C16 = 0.92387953251128676f, S16 = 0.38268343236508977f;
    z[5]  = cmul(z[5],  make_float2( C16,  S16));   // e=1
    z[9]  = cmul(z[9],  make_float2( C8,   C8 ));   // e=2
    z[13] = cmul(z[13], make_float2( S16,  C16));   // e=3
    z[6]  = cmul(z[6],  make_float2( C8,   C8 ));   // e=2
    z[10] = make_float2(-z[10].y, z[10].x);         // e=4
    z[14] = cmul(z[14], make_float2(-C8,   C8 ));   // e=6
    z[7]  = cmul(z[7],  make_float2( S16,  C16));   // e=3
    z[11] = cmul(z[11], make_float2(-C8,   C8 ));   // e=6
    z[15] = cmul(z[15], make_float2(-C16, -S16));   // e=9
    ifft4(z[0],  z[1],  z[2],  z[3]);
    ifft4(z[4],  z[5],  z[6],  z[7]);
    ifft4(z[8],  z[9],  z[10], z[11]);
    ifft4(z[12], z[13], z[14], z[15]);
}

#define LDS_FENCE() do { \
    asm volatile("s_waitcnt lgkmcnt(0)" ::: "memory"); \
    __builtin_amdgcn_sched_barrier(0); \
} while (0)

// cos/sin(pi*p/16), p=0..15 (pack rotation constants)
__device__ __constant__ float ROTC[16] = {
    1.0f, 0.98078528f, 0.92387953f, 0.83146961f, 0.70710678f, 0.55557023f,
    0.38268343f, 0.19509032f, 0.0f, -0.19509032f, -0.38268343f, -0.55557023f,
    -0.70710678f, -0.83146961f, -0.92387953f, -0.98078528f };
__device__ __constant__ float ROTS[16] = {
    0.0f, 0.19509032f, 0.38268343f, 0.55557023f, 0.70710678f, 0.83146961f,
    0.92387953f, 0.98078528f, 1.0f, 0.98078528f, 0.92387953f, 0.83146961f,
    0.70710678f, 0.55557023f, 0.38268343f, 0.19509032f };

// ---------------------------------------------------------------------------
// 256 threads = 4 waves; wave w handles frames (blk*8 + w) and (blk*8 + w+4).
// Per frame (wave-private, no __syncthreads in the loop):
//  P0: 32 coalesced dword loads (mag/ph at 64q+lane), sincos once per bin,
//      stage complex X[k] to wave LDS buffer (Xk also kept in registers).
//  P1: pack Zf (Hermitian trick; mirror X[1024-k] from LDS, Nyquist from
//      regs), in-register iFFT16 over p, twiddle wq^m (chained), store B.
//  P2a: iFFT4 over s + w64 twiddle, lane-private in-place.
//  P2b: iFFT16 over r -> y; fftshift+window -> ds_add into shared acc.
// Layout rotation: addr(row m, col q) = 64m + ((q+m)&63).
// ---------------------------------------------------------------------------
__global__ __launch_bounds__(256, 2) void istft_kernel(
        const float* __restrict__ mag, const float* __restrict__ ph,
        const float* __restrict__ rs, float* __restrict__ out, int out_size) {
    __shared__ float2 fbuf[WAVES * 1024];    // 32 KB: 8 KB per wave
    __shared__ float  acc[ACCN];             // 22.5 KB shared OLA buffer

    const int tid  = threadIdx.x;
    const int wave = tid >> 6;
    const int lane = tid & 63;
    const int m_   = lane & 15;
    const int g_   = lane >> 4;
    float2* buf = fbuf + wave * 1024;
    const int frame0 = blockIdx.x * FPB;

    for (int i = tid; i < ACCN; i += 256) acc[i] = 0.0f;

    // ---- frame-invariant per-lane constants ----
    float2 wpq;                                   // e^{i pi q/1024}
    sincospif((float)lane * (1.0f / 1024.0f), &wpq.y, &wpq.x);
    float2 wq = cmul(wpq, wpq);                   // e^{2pi i q/1024}
    float2 tw64[4][3];                            // e^{2pi i (4g+i)u/64}, u=1..3
    #pragma unroll
    for (int i = 0; i < 4; ++i)
        #pragma unroll
        for (int u = 1; u < 4; ++u)
            sincospif((float)((4 * g_ + i) * u) * (1.0f / 32.0f),
                      &tw64[i][u - 1].y, &tw64[i][u - 1].x);
    const float2* rs2 = (const float2*)rs;
    float2 rsv[16];                               // rs2[lane + 64w]
    #pragma unroll
    for (int w = 0; w < 16; ++w) rsv[w] = rs2[lane + 64 * w];

    __syncthreads();                              // acc zero visible

    for (int j = 0; j < FPB / WAVES; ++j) {
        const int fi    = wave + WAVES * j;
        const size_t fb = (size_t)(frame0 + fi) * NBINS;
        const float* magf = mag + fb;
        const float* phf  = ph  + fb;

        // ---- P0: coalesced load + sincos + stage X into LDS ----
        float mg[16], pp[16];
        #pragma unroll
        for (int q = 0; q < 16; ++q) mg[q] = magf[64 * q + lane];
        #pragma unroll
        for (int q = 0; q < 16; ++q) pp[q] = phf[64 * q + lane];
        float nyqm = magf[1024], nyqp = phf[1024];      // uniform loads
        float xr[16], xi[16];
        #pragma unroll
        for (int q = 0; q < 16; ++q) {
            float s, c;
            __sincosf(pp[q], &s, &c);
            xr[q] = mg[q] * c;
            xi[q] = mg[q] * s;
        }
        // previous frame's LDS reads complete before overwrite
        LDS_FENCE();
        #pragma unroll
        for (int q = 0; q < 16; ++q)
            buf[64 * q + lane] = make_float2(xr[q], xi[q]);
        LDS_FENCE();

        // ---- P1: pack + iFFT16 over p ----
        float nc, ns;
        __sincosf(nyqp, &ns, &nc);
        const float2 Xnyq = make_float2(nyqm * nc, 0.0f);
        float2 z[16];
        #pragma unroll
        for (int p = 0; p < 16; ++p) {
            const int k = lane + 64 * p;
            float2 Xk = make_float2(xr[p], (k == 0) ? 0.0f : xi[p]);
            float2 Xm = (k == 0) ? Xnyq : buf[1024 - k];
            float2 tp = make_float2(ROTC[p] * wpq.x - ROTS[p] * wpq.y,
                                    ROTC[p] * wpq.y + ROTS[p] * wpq.x);
            float Er = 0.5f * (Xk.x + Xm.x), Ei = 0.5f * (Xk.y - Xm.y);
            float Tr = Xm.x - Xk.x,          Ti = -(Xm.y + Xk.y);
            float Or = 0.5f * (tp.x * Ti + tp.y * Tr);
            float Oi = 0.5f * (tp.y * Ti - tp.x * Tr);
            z[p] = make_float2(Er + Or, Ei + Oi);
        }
        ifft16(z);

        LDS_FENCE();
        {
            float2 wcur = make_float2(1.0f, 0.0f);       // wq^m chain
            #pragma unroll
            for (int m = 0; m < 16; ++m) {
                float2 B = cmul(z[4 * (m & 3) + (m >> 2)], wcur);
                buf[64 * m + ((lane + m) & 63)] = B;
                wcur = cmul(wcur, wq);
            }
        }
        LDS_FENCE();

        // ---- P2a: iFFT4 over s + twiddle, lane-private in place ----
        float2 br[4][4];
        #pragma unroll
        for (int i = 0; i < 4; ++i)
            #pragma unroll
            for (int s = 0; s < 4; ++s)
                br[i][s] = buf[64 * m_ + ((4 * g_ + i + 16 * s + m_) & 63)];
        #pragma unroll
        for (int i = 0; i < 4; ++i) {
            ifft4(br[i][0], br[i][1], br[i][2], br[i][3]);
            br[i][1] = cmul(br[i][1], tw64[i][0]);
            br[i][2] = cmul(br[i][2], tw64[i][1]);
            br[i][3] = cmul(br[i][3], tw64[i][2]);
        }
        #pragma unroll
        for (int i = 0; i < 4; ++i)
            #pragma unroll
            for (int u = 0; u < 4; ++u)
                buf[64 * m_ + ((4 * g_ + i + 16 * u + m_) & 63)] = br[i][u];
        LDS_FENCE();

        // ---- P2b: iFFT16 over r ----
        float2 d[16];
        #pragma unroll
        for (int r = 0; r < 16; ++r)
            d[r] = buf[64 * m_ + ((r + 16 * g_ + m_) & 63)];
        ifft16(d);

        // ---- OLA: y[n], n = m_+16g_+64v ; t2 = m_+16g_+64*((v+8)&15) ----
        const int aBase = fi * HOP;
        #pragma unroll
        for (int v = 0; v < 16; ++v) {
            float2 y = d[4 * (v & 3) + (v >> 2)];
            const int w  = (v + 8) & 15;
            const int t2 = m_ + 16 * g_ + 64 * w;
            const float2 r = rsv[w];
            __hip_atomic_fetch_add(&acc[aBase + 2 * t2],     y.x * r.x,
                                   __ATOMIC_RELAXED, __HIP_MEMORY_SCOPE_WORKGROUP);
            __hip_atomic_fetch_add(&acc[aBase + 2 * t2 + 1], y.y * r.y,
                                   __ATOMIC_RELAXED, __HIP_MEMORY_SCOPE_WORKGROUP);
        }
    }
    __syncthreads();

    // writeback: p = frame0*HOP + a - 1536; interior plain, seams atomic
    const int base = frame0 * HOP - 1536;
    for (int a = tid; a < ACCN; a += 256) {
        int p = base + a;
        if (p < 0 || p >= out_size) continue;
        float v = acc[a];
        if (a >= (WIN - HOP) && a < FPB * HOP) out[p] = v;
        else                                   atomicAdd(out + p, v);
    }
}

extern "C" void kernel_launch(void* const* d_in, const int* in_sizes, int n_in,
                              void* d_out, int out_size, void* d_ws, size_t ws_size,
                              hipStream_t stream) {
    const float* mag = (const float*)d_in[0];
    const float* ph  = (const float*)d_in[1];
    float* out = (float*)d_out;
    float* rs  = (float*)d_ws;

    hipMemsetAsync(d_out, 0, (size_t)out_size * sizeof(float), stream);
    init_rs_kernel<<<(WIN + 255) / 256, 256, 0, stream>>>(rs);
    istft_kernel<<<NFRAMES / FPB, 256, 0, stream>>>(mag, ph, rs, out, out_size);
}

// Round 7
// 85.967 us; speedup vs baseline: 3.6938x; 3.1432x over previous
//
#include <hip/hip_runtime.h>

#define WIN      2048
#define HOP      512
#define NFRAMES  16384
#define NBINS    1025      // WIN/2 + 1
#define FPB      8         // frames per block

// ---------------------------------------------------------------------------
// init: synthesis window rs[j] = (hamming/sqrt(4094)) / env, folded with the
// 1/1024 normalization of the half-size complex IFFT.
// ---------------------------------------------------------------------------
__global__ void init_rs_kernel(float* __restrict__ rs) {
    int i = blockIdx.x * blockDim.x + threadIdx.x;
    if (i >= WIN) return;
    const float inv2047 = 1.0f / 2047.0f;
    const float scale   = rsqrtf(4094.0f);
    float sw = (0.54f - 0.46f * cospif(2.0f * (float)i * inv2047)) * scale;
    int   m0 = i & 511;
    float env = 0.0f;
    #pragma unroll
    for (int r = 0; r < 4; ++r) {
        int   m = m0 + 512 * r;
        float h = (0.54f - 0.46f * cospif(2.0f * (float)m * inv2047)) * scale;
        env += h * h;
    }
    rs[i] = sw / env * (1.0f / 1024.0f);
}

__device__ __forceinline__ int pidx(int a) { return a + (a >> 3); }
__device__ __forceinline__ float2 cmul(float2 a, float2 b) {
    return make_float2(a.x * b.x - a.y * b.y, a.x * b.y + a.y * b.x);
}

// ---------------------------------------------------------------------------
// one workgroup (256 threads) per 8 frames, processed IN ORDER. Per frame:
//  A: spectrum X[0..1024] -> LDS (hw sincos); also flush of prev chunk
//  B+s0: half-size pack fused with radix-4 stage0
//  s1..s3: radix-4 Stockham, reg-hoisted twiddles
//  s4+OLA: twiddle-free last stage fused with fftshift/window -> RING acc
//  flush: chunk fi of the ring is now complete -> store/atomic to global,
//         zero the slot for reuse (no extra barrier needed: 5 barriers
//         separate this from the next OLA write to the same slot).
// Ring = 4 chunks x 512 floats (frame fi touches chunks fi..fi+3).
// Chunks 0,1,2 and 8,9,10 are block-boundary seams -> atomicAdd; 3..7 plain.
// ---------------------------------------------------------------------------
__global__ __launch_bounds__(256, 4) void istft_kernel(
        const float* __restrict__ mag, const float* __restrict__ ph,
        const float* __restrict__ rs, float* __restrict__ out, int out_size) {
    __shared__ float2 bufA[1152];        // 1024 + pad      (9216 B)
    __shared__ float2 bufB[1152];        //                 (9216 B)
    __shared__ float2 ring[1024];        // 4 x 512 floats  (8192 B)

    const int tid    = threadIdx.x;
    const int frame0 = blockIdx.x * FPB;

    // ---- frame-invariant per-thread constants ----
    float2 wpk;                                    // e^{2pi i tid/2048}
    sincospif((float)tid * (1.0f / 1024.0f), &wpk.y, &wpk.x);
    float2 wst[4], w2st[4];
    wst[0] = cmul(wpk, wpk);                       // e^{2pi i tid/1024}
    sincospif((float)(tid & ~3)  * (1.0f / 512.0f), &wst[1].y, &wst[1].x);
    sincospif((float)(tid & ~15) * (1.0f / 512.0f), &wst[2].y, &wst[2].x);
    sincospif((float)(tid & ~63) * (1.0f / 512.0f), &wst[3].y, &wst[3].x);
    #pragma unroll
    for (int t = 0; t < 4; ++t) w2st[t] = cmul(wst[t], wst[t]);

    const float2* rs2 = (const float2*)rs;
    const float2 r0 = rs2[tid], r1 = rs2[tid + 256],
                 r2 = rs2[tid + 512], r3 = rs2[tid + 768];
    const float RT = 0.70710678118654752f;         // sqrt(2)/2

    for (int i = tid; i < 1024; i += 256) ring[i] = make_float2(0.0f, 0.0f);
    // (barrier inside first frame's pipeline orders zero before first OLA)

    for (int fi = 0; fi < FPB; ++fi) {
        const float* magf = mag + (size_t)(frame0 + fi) * NBINS;
        const float* phf  = ph  + (size_t)(frame0 + fi) * NBINS;

        // A: spectrum into bufB (raw indexing)
        for (int k = tid; k < NBINS; k += 256) {
            float s, c;
            __sincosf(phf[k], &s, &c);
            float m = magf[k];
            float re = m * c, im = m * s;
            if (k == 0 || k == 1024) im = 0.0f;
            bufB[k] = make_float2(re, im);
        }
        __syncthreads();

        // B + stage0 (fused in registers) -> bufA
        {
            float2 z[4];
            #pragma unroll
            for (int j = 0; j < 4; ++j) {
                int k = tid + j * 256;
                float2 Xk = bufB[k];
                float2 Xm = bufB[1024 - k];
                float2 wj;                         // wpk * e^{i pi j/4}
                if      (j == 0) wj = wpk;
                else if (j == 1) wj = make_float2(RT * (wpk.x - wpk.y), RT * (wpk.x + wpk.y));
                else if (j == 2) wj = make_float2(-wpk.y, wpk.x);
                else             wj = make_float2(-RT * (wpk.x + wpk.y), RT * (wpk.x - wpk.y));
                float Er = 0.5f * (Xk.x + Xm.x), Ei = 0.5f * (Xk.y - Xm.y);
                float Tr = Xm.x - Xk.x,          Ti = -Xm.y - Xk.y;
                float Or = 0.5f * (wj.x * Ti + wj.y * Tr);
                float Oi = 0.5f * (wj.y * Ti - wj.x * Tr);
                z[j] = make_float2(Er + Or, Ei + Oi);
            }
            float2 w = wst[0], w2 = w2st[0];
            float2 u0 = make_float2(z[0].x + z[2].x, z[0].y + z[2].y);
            float  ar = z[0].x - z[2].x, ai = z[0].y - z[2].y;
            float2 u1 = make_float2(ar * w.x - ai * w.y, ar * w.y + ai * w.x);
            float2 u2 = make_float2(z[1].x + z[3].x, z[1].y + z[3].y);
            float  br = z[1].x - z[3].x, bi = z[1].y - z[3].y;
            float2 u3 = make_float2(-br * w.y - bi * w.x, br * w.x - bi * w.y);
            const int base = 4 * tid;              // tid + 3*G, G=tid, s4=1
            bufA[pidx(base)]     = make_float2(u0.x + u2.x, u0.y + u2.y);
            bufA[pidx(base + 1)] = make_float2(u1.x + u3.x, u1.y + u3.y);
            float dr = u0.x - u2.x, di = u0.y - u2.y;
            bufA[pidx(base + 2)] = make_float2(dr * w2.x - di * w2.y, dr * w2.y + di * w2.x);
            float er = u1.x - u3.x, ei = u1.y - u3.y;
            bufA[pidx(base + 3)] = make_float2(er * w2.x - ei * w2.y, er * w2.y + ei * w2.x);
        }
        __syncthreads();

        // stages 1..3 (A->B->A->B)
        {
            float2* src = bufA;
            float2* dst = bufB;
            #pragma unroll
            for (int t = 1; t < 4; ++t) {
                const int s4 = 1 << (2 * t);
                const int G  = tid & ~(s4 - 1);
                float2 x0 = src[pidx(tid)];
                float2 x1 = src[pidx(tid + 256)];
                float2 x2 = src[pidx(tid + 512)];
                float2 x3 = src[pidx(tid + 768)];
                float2 w = wst[t], w2 = w2st[t];
                float2 u0 = make_float2(x0.x + x2.x, x0.y + x2.y);
                float  ar = x0.x - x2.x, ai = x0.y - x2.y;
                float2 u1 = make_float2(ar * w.x - ai * w.y, ar * w.y + ai * w.x);
                float2 u2 = make_float2(x1.x + x3.x, x1.y + x3.y);
                float  br = x1.x - x3.x, bi = x1.y - x3.y;
                float2 u3 = make_float2(-br * w.y - bi * w.x, br * w.x - bi * w.y);
                const int base = tid + 3 * G;
                dst[pidx(base)]          = make_float2(u0.x + u2.x, u0.y + u2.y);
                dst[pidx(base + s4)]     = make_float2(u1.x + u3.x, u1.y + u3.y);
                float dr = u0.x - u2.x, di = u0.y - u2.y;
                dst[pidx(base + 2 * s4)] = make_float2(dr * w2.x - di * w2.y, dr * w2.y + di * w2.x);
                float er = u1.x - u3.x, ei = u1.y - u3.y;
                dst[pidx(base + 3 * s4)] = make_float2(er * w2.x - ei * w2.y, er * w2.y + ei * w2.x);
                __syncthreads();
                float2* tmp = src; src = dst; dst = tmp;
            }
        }
        // data now in bufB

        // stage4 (w = w2 = 1) fused with fftshift/window/OLA into the ring
        {
            float2 x0 = bufB[pidx(tid)];
            float2 x1 = bufB[pidx(tid + 256)];
            float2 x2 = bufB[pidx(tid + 512)];
            float2 x3 = bufB[pidx(tid + 768)];
            float2 u0 = make_float2(x0.x + x2.x, x0.y + x2.y);
            float2 u1 = make_float2(x0.x - x2.x, x0.y - x2.y);
            float2 u2 = make_float2(x1.x + x3.x, x1.y + x3.y);
            float2 u3 = make_float2(-(x1.y - x3.y), x1.x - x3.x);   // i*(x1-x3)
            const int A0 = fi * 256;
            float2 y, a;
            int idx;
            // n=tid       -> t2=tid+512 (fftshift), window r2
            y = make_float2(u0.x + u2.x, u0.y + u2.y);
            idx = (A0 + tid + 512) & 1023;
            a = ring[idx];
            ring[idx] = make_float2(a.x + y.x * r2.x, a.y + y.y * r2.y);
            // n=tid+256   -> t2=tid+768, window r3
            y = make_float2(u1.x + u3.x, u1.y + u3.y);
            idx = (A0 + tid + 768) & 1023;
            a = ring[idx];
            ring[idx] = make_float2(a.x + y.x * r3.x, a.y + y.y * r3.y);
            // n=tid+512   -> t2=tid, window r0
            y = make_float2(u0.x - u2.x, u0.y - u2.y);
            idx = (A0 + tid) & 1023;
            a = ring[idx];
            ring[idx] = make_float2(a.x + y.x * r0.x, a.y + y.y * r0.y);
            // n=tid+768   -> t2=tid+256, window r1
            y = make_float2(u1.x - u3.x, u1.y - u3.y);
            idx = (A0 + tid + 256) & 1023;
            a = ring[idx];
            ring[idx] = make_float2(a.x + y.x * r1.x, a.y + y.y * r1.y);
        }
        __syncthreads();

        // flush chunk fi (ring slot fi&3): complete, since frames are in
        // order and frame fi was this chunk's last contributor.
        {
            const int cidx = (fi & 3) * 256 + tid;       // float2 index
            float2 v = ring[cidx];
            ring[cidx] = make_float2(0.0f, 0.0f);        // thread-private RMW
            long p = (long)frame0 * HOP + fi * HOP + 2 * tid - 1536;
            if (fi >= 3) {                               // interior: plain
                if (p >= 0 && p < out_size)         out[p]     = v.x;
                if (p + 1 >= 0 && p + 1 < out_size) out[p + 1] = v.y;
            } else {                                     // seam: atomic
                if (p >= 0 && p < out_size)         atomicAdd(out + p,     v.x);
                if (p + 1 >= 0 && p + 1 < out_size) atomicAdd(out + p + 1, v.y);
            }
        }
        // no barrier: 5 barriers separate this from the next OLA write to
        // this slot, and read+zero above are thread-private.
    }

    // tail: chunks 8,9,10 (ring slots 0,1,2) are partial sums -> atomic
    #pragma unroll
    for (int lc = 8; lc <= 10; ++lc) {
        const int cidx = (lc & 3) * 256 + tid;
        float2 v = ring[cidx];
        long p = (long)frame0 * HOP + lc * HOP + 2 * tid - 1536;
        if (p >= 0 && p < out_size)         atomicAdd(out + p,     v.x);
        if (p + 1 >= 0 && p + 1 < out_size) atomicAdd(out + p + 1, v.y);
    }
}

extern "C" void kernel_launch(void* const* d_in, const int* in_sizes, int n_in,
                              void* d_out, int out_size, void* d_ws, size_t ws_size,
                              hipStream_t stream) {
    const float* mag = (const float*)d_in[0];
    const float* ph  = (const float*)d_in[1];
    float* out = (float*)d_out;
    float* rs  = (float*)d_ws;

    hipMemsetAsync(d_out, 0, (size_t)out_size * sizeof(float), stream);
    init_rs_kernel<<<(WIN + 255) / 256, 256, 0, stream>>>(rs);
    istft_kernel<<<NFRAMES / FPB, 256, 0, stream>>>(mag, ph, rs, out, out_size);
}